// Round 4
// baseline (905.187 us; speedup 1.0000x reference)
//
#include <hip/hip_runtime.h>
#include <hip/hip_bf16.h>
#include <hip/hip_fp16.h>

// Problem dims
#define A_DIM 4608   // C*9 patch-feature rows
#define L_DIM 4096   // (H/3)*(W/3) spatial columns
#define CH    512
#define H_DIM 192
#define W_DIM 192

// GEMM tile
#define BM 256       // sty rows per block
#define BN 128       // img rows (columns of S2) per block
#define BK 32        // k per stage (4 chunks of 8 halves)

typedef _Float16 half8 __attribute__((ext_vector_type(8)));
typedef float   floatx4 __attribute__((ext_vector_type(4)));
typedef float   floatx16 __attribute__((ext_vector_type(16)));

// ---------------------------------------------------------------------------
// Pass 1: unfold(x) -> k-chunk-major f16 hi/lo split + 1/row-norm.
// Output layout: U[(l>>3)*A_DIM + a][8] i.e. chunk-major so the GEMM's
// global_load_lds staging is contiguous AND yields a conflict-free LDS layout.
// ---------------------------------------------------------------------------
__global__ __launch_bounds__(256) void prep_kernel(
    const float* __restrict__ x0, const float* __restrict__ x1,
    _Float16* __restrict__ Uhi0, _Float16* __restrict__ Ulo0,
    _Float16* __restrict__ Uhi1, _Float16* __restrict__ Ulo1,
    float* __restrict__ nr0, float* __restrict__ nr1) {
  const int which = blockIdx.z;
  const float* __restrict__ x = which ? x1 : x0;
  _Float16* __restrict__ Uhi = which ? Uhi1 : Uhi0;
  _Float16* __restrict__ Ulo = which ? Ulo1 : Ulo0;
  float* __restrict__ nrecip = which ? nr1 : nr0;

  const int c = blockIdx.x, kh = blockIdx.y;
  const int a0 = c * 9 + kh * 3;
  const float* __restrict__ xb = x + (size_t)c * (H_DIM * W_DIM) + kh * W_DIM;
  const int t = threadIdx.x;

  float ss0 = 0.f, ss1 = 0.f, ss2 = 0.f;
#pragma unroll
  for (int it = 0; it < 16; ++it) {
    const int l = it * 256 + t;
    const int ph = l >> 6, pw = l & 63;
    const float* __restrict__ p = xb + (3 * ph) * W_DIM + 3 * pw;
    const float v0 = p[0], v1 = p[1], v2 = p[2];
    ss0 += v0 * v0; ss1 += v1 * v1; ss2 += v2 * v2;
    const _Float16 h0 = (_Float16)v0, h1 = (_Float16)v1, h2 = (_Float16)v2;
    // chunk-major: element e=(l&7) of chunk c8=(l>>3) of row a
    const size_t base = ((size_t)(l >> 3) * A_DIM) * 8 + (l & 7);
    Uhi[base + (size_t)(a0 + 0) * 8] = h0;
    Uhi[base + (size_t)(a0 + 1) * 8] = h1;
    Uhi[base + (size_t)(a0 + 2) * 8] = h2;
    Ulo[base + (size_t)(a0 + 0) * 8] = (_Float16)(v0 - (float)h0);
    Ulo[base + (size_t)(a0 + 1) * 8] = (_Float16)(v1 - (float)h1);
    Ulo[base + (size_t)(a0 + 2) * 8] = (_Float16)(v2 - (float)h2);
  }
  __shared__ float wss[3][4];
  const int wid = t >> 6, lane = t & 63;
  float s[3] = {ss0, ss1, ss2};
#pragma unroll
  for (int kw = 0; kw < 3; ++kw) {
    float v = s[kw];
#pragma unroll
    for (int off = 32; off > 0; off >>= 1) v += __shfl_down(v, off, 64);
    if (lane == 0) wss[kw][wid] = v;
  }
  __syncthreads();
  if (t < 3) {
    const float tot = wss[t][0] + wss[t][1] + wss[t][2] + wss[t][3];
    nrecip[a0 + t] = 1.0f / sqrtf(tot);
  }
}

// ---------------------------------------------------------------------------
// Pass 2: D[i,j] = sty_i . img_j, 3-term f16 split (hi*hi + hi*lo + lo*hi),
// 32x32x16 MFMA, 256x128 tile (4 waves, each 128x64), fused column max/argmax.
//
// LDS layout per buffer: [kchunk][row][8 halves] (chunk-major, matches the
// global layout). GLDS dest = t*16B per call -> global source contiguous
// (1 KB/wave) AND fragment reads are base + l31*16 (linear per half-wave,
// the R1-verified conflict-free pattern).
// ---------------------------------------------------------------------------
#define GLDS(g, l)                                                          \
  __builtin_amdgcn_global_load_lds(                                        \
      (const __attribute__((address_space(1))) void*)(g),                   \
      (__attribute__((address_space(3))) void*)(l), 16, 0, 0)

__global__ __launch_bounds__(256, 2) void gemm_max_kernel(
    const _Float16* __restrict__ Shi, const _Float16* __restrict__ Slo,
    const _Float16* __restrict__ Ihi, const _Float16* __restrict__ Ilo,
    const float* __restrict__ img_nr,
    unsigned long long* __restrict__ packed) {
  __shared__ _Float16 sAh[4 * BM * 8];   // 16 KB
  __shared__ _Float16 sAl[4 * BM * 8];   // 16 KB
  __shared__ _Float16 sBh[4 * BN * 8];   // 8 KB
  __shared__ _Float16 sBl[4 * BN * 8];   // 8 KB

  const int t = threadIdx.x;
  const int lane = t & 63, wv = t >> 6;
  const int wvr = wv >> 1, wvc = wv & 1;       // 2x2 waves; wave tile 128x64
  const int row0 = blockIdx.y * BM;            // sty rows (i)
  const int col0 = blockIdx.x * BN;            // img rows (j)
  const int l31 = lane & 31, hs = lane >> 5;

  floatx16 acc[4][2];
#pragma unroll
  for (int rf = 0; rf < 4; ++rf)
#pragma unroll
    for (int cf = 0; cf < 2; ++cf) acc[rf][cf] = (floatx16)0.f;

  // Staging source pointers (halves). One kchunk plane = A_DIM*8 halves.
  const size_t CH8 = (size_t)A_DIM * 8;
  const _Float16* pAh = Shi + (size_t)(row0 + t) * 8;
  const _Float16* pAl = Slo + (size_t)(row0 + t) * 8;
  const _Float16* pBh = Ihi + (size_t)(col0 + (t & 127)) * 8 + (size_t)(t >> 7) * CH8;
  const _Float16* pBl = Ilo + (size_t)(col0 + (t & 127)) * 8 + (size_t)(t >> 7) * CH8;
  const int dA = t * 8;  // LDS dest (halves): t*16 bytes per call

  for (int ks = 0; ks < L_DIM / BK; ++ks) {
    __syncthreads();  // previous compute done before overwrite
    GLDS(pAh + 0 * CH8, &sAh[dA + 0 * 2048]);
    GLDS(pAh + 1 * CH8, &sAh[dA + 1 * 2048]);
    GLDS(pAh + 2 * CH8, &sAh[dA + 2 * 2048]);
    GLDS(pAh + 3 * CH8, &sAh[dA + 3 * 2048]);
    GLDS(pAl + 0 * CH8, &sAl[dA + 0 * 2048]);
    GLDS(pAl + 1 * CH8, &sAl[dA + 1 * 2048]);
    GLDS(pAl + 2 * CH8, &sAl[dA + 2 * 2048]);
    GLDS(pAl + 3 * CH8, &sAl[dA + 3 * 2048]);
    GLDS(pBh + 0 * CH8, &sBh[dA]);
    GLDS(pBh + 2 * CH8, &sBh[dA + 2048]);
    GLDS(pBl + 0 * CH8, &sBl[dA]);
    GLDS(pBl + 2 * CH8, &sBl[dA + 2048]);
    pAh += 4 * CH8; pAl += 4 * CH8; pBh += 4 * CH8; pBl += 4 * CH8;
    __syncthreads();  // loads visible

#pragma unroll
    for (int kk = 0; kk < 2; ++kk) {
      half8 ah[4], al[4], bh[2], bl[2];
      const int kc = kk * 2 + hs;  // kchunk this lane-half consumes
#pragma unroll
      for (int rf = 0; rf < 4; ++rf) {
        const int idx = (kc * BM + wvr * 128 + rf * 32 + l31) * 8;
        ah[rf] = *(const half8*)&sAh[idx];
        al[rf] = *(const half8*)&sAl[idx];
      }
#pragma unroll
      for (int cf = 0; cf < 2; ++cf) {
        const int idx = (kc * BN + wvc * 64 + cf * 32 + l31) * 8;
        bh[cf] = *(const half8*)&sBh[idx];
        bl[cf] = *(const half8*)&sBl[idx];
      }
#pragma unroll
      for (int rf = 0; rf < 4; ++rf)
#pragma unroll
        for (int cf = 0; cf < 2; ++cf) {
          acc[rf][cf] = __builtin_amdgcn_mfma_f32_32x32x16_f16(
              ah[rf], bh[cf], acc[rf][cf], 0, 0, 0);
          acc[rf][cf] = __builtin_amdgcn_mfma_f32_32x32x16_f16(
              ah[rf], bl[cf], acc[rf][cf], 0, 0, 0);
          acc[rf][cf] = __builtin_amdgcn_mfma_f32_32x32x16_f16(
              al[rf], bh[cf], acc[rf][cf], 0, 0, 0);
        }
    }
  }

  // Epilogue: v[i,j] = img_nr[i]*D[i,j]; column max+argmax (first-index wins).
  // 32x32 C/D layout: col = lane&31, row = (reg&3) + 8*(reg>>2) + 4*(lane>>5).
#pragma unroll
  for (int cf = 0; cf < 2; ++cf) {
    const int j = col0 + wvc * 64 + cf * 32 + l31;
    float best = -3.4e38f;
    int bi = 0x7FFFFFFF;
#pragma unroll
    for (int rf = 0; rf < 4; ++rf) {
      const int base_i = row0 + wvr * 128 + rf * 32 + 4 * hs;
#pragma unroll
      for (int g = 0; g < 4; ++g) {
        const floatx4 n4 = *(const floatx4*)&img_nr[base_i + 8 * g];
#pragma unroll
        for (int r = 0; r < 4; ++r) {
          const int i = base_i + 8 * g + r;
          const float v = acc[rf][cf][g * 4 + r] * n4[r];
          if (v > best) { best = v; bi = i; }  // ascending i => first wins
        }
      }
    }
    // combine the two half-wave row sets (lane ^ 32 holds the same column)
    const float ov = __shfl_xor(best, 32, 64);
    const int oi = __shfl_xor(bi, 32, 64);
    if (ov > best || (ov == best && oi < bi)) { best = ov; bi = oi; }
    if (hs == 0) {
      const unsigned u = __float_as_uint(best);
      const unsigned key = (u & 0x80000000u) ? ~u : (u | 0x80000000u);
      const unsigned long long pk =
          ((unsigned long long)key << 32) | (unsigned)(~(unsigned)bi);
      atomicMax(&packed[j], pk);
    }
  }
}

// ---------------------------------------------------------------------------
// Pass 3: decode packed, apply sty_nr[j]; out[0..A)=nearest, out[A..2A)=max.
// ---------------------------------------------------------------------------
__global__ __launch_bounds__(256) void finalize_kernel(
    const unsigned long long* __restrict__ packed,
    const float* __restrict__ sty_nr, float* __restrict__ out) {
  const int j = blockIdx.x * 256 + threadIdx.x;
  if (j >= A_DIM) return;
  const unsigned long long p = packed[j];
  const unsigned key = (unsigned)(p >> 32);
  const unsigned u = (key & 0x80000000u) ? (key ^ 0x80000000u) : ~key;
  const float v = __uint_as_float(u);
  const int idx = (int)(~(unsigned)(p & 0xFFFFFFFFu));
  out[j] = (float)idx;
  out[A_DIM + j] = v * sty_nr[j];
}

extern "C" void kernel_launch(void* const* d_in, const int* in_sizes, int n_in,
                              void* d_out, int out_size, void* d_ws, size_t ws_size,
                              hipStream_t stream) {
  const float* model = (const float*)d_in[0];  // img side
  const float* style = (const float*)d_in[1];  // sty side
  float* out = (float*)d_out;
  char* ws = (char*)d_ws;

  const size_t usz = (size_t)A_DIM * L_DIM * 2;  // one f16 matrix: 37,748,736 B
  _Float16* img_hi = (_Float16*)(ws);
  _Float16* img_lo = (_Float16*)(ws + usz);
  _Float16* sty_hi = (_Float16*)(ws + 2 * usz);
  _Float16* sty_lo = (_Float16*)(ws + 3 * usz);
  float* img_nr = (float*)(ws + 4 * usz);
  float* sty_nr = img_nr + A_DIM;
  unsigned long long* packed = (unsigned long long*)(img_nr + 2 * A_DIM);

  hipMemsetAsync(packed, 0, (size_t)A_DIM * 8, stream);
  prep_kernel<<<dim3(CH, 3, 2), 256, 0, stream>>>(
      model, style, img_hi, img_lo, sty_hi, sty_lo, img_nr, sty_nr);
  gemm_max_kernel<<<dim3(A_DIM / BN, A_DIM / BM), 256, 0, stream>>>(
      sty_hi, sty_lo, img_hi, img_lo, img_nr, packed);
  finalize_kernel<<<18, 256, 0, stream>>>(packed, sty_nr, out);
}

// Round 5
// 798.154 us; speedup vs baseline: 1.1341x; 1.1341x over previous
//
#include <hip/hip_runtime.h>
#include <hip/hip_bf16.h>
#include <hip/hip_fp16.h>

// Problem dims
#define A_DIM 4608   // C*9 patch-feature rows
#define L_DIM 4096   // (H/3)*(W/3) spatial columns
#define CH    512
#define H_DIM 192
#define W_DIM 192

// GEMM tile
#define BM 128
#define BN 128
#define BK 32        // 4 kchunks of 8 halves per stage
#define NS (L_DIM / BK)

typedef _Float16 half8 __attribute__((ext_vector_type(8)));
typedef float   floatx4 __attribute__((ext_vector_type(4)));
typedef float   floatx16 __attribute__((ext_vector_type(16)));

// ---------------------------------------------------------------------------
// Pass 1: unfold(x) -> k-chunk-major f16 hi/lo split + 1/row-norm.
// Layout: U[(l>>3)*A_DIM + a][8]  (chunk-major: GLDS staging contiguous AND
// conflict-free LDS reads — verified R4: SQ_LDS_BANK_CONFLICT = 0).
// ---------------------------------------------------------------------------
__global__ __launch_bounds__(256) void prep_kernel(
    const float* __restrict__ x0, const float* __restrict__ x1,
    _Float16* __restrict__ Uhi0, _Float16* __restrict__ Ulo0,
    _Float16* __restrict__ Uhi1, _Float16* __restrict__ Ulo1,
    float* __restrict__ nr0, float* __restrict__ nr1) {
  const int which = blockIdx.z;
  const float* __restrict__ x = which ? x1 : x0;
  _Float16* __restrict__ Uhi = which ? Uhi1 : Uhi0;
  _Float16* __restrict__ Ulo = which ? Ulo1 : Ulo0;
  float* __restrict__ nrecip = which ? nr1 : nr0;

  const int c = blockIdx.x, kh = blockIdx.y;
  const int a0 = c * 9 + kh * 3;
  const float* __restrict__ xb = x + (size_t)c * (H_DIM * W_DIM) + kh * W_DIM;
  const int t = threadIdx.x;

  float ss0 = 0.f, ss1 = 0.f, ss2 = 0.f;
#pragma unroll
  for (int it = 0; it < 16; ++it) {
    const int l = it * 256 + t;
    const int ph = l >> 6, pw = l & 63;
    const float* __restrict__ p = xb + (3 * ph) * W_DIM + 3 * pw;
    const float v0 = p[0], v1 = p[1], v2 = p[2];
    ss0 += v0 * v0; ss1 += v1 * v1; ss2 += v2 * v2;
    const _Float16 h0 = (_Float16)v0, h1 = (_Float16)v1, h2 = (_Float16)v2;
    const size_t base = ((size_t)(l >> 3) * A_DIM) * 8 + (l & 7);
    Uhi[base + (size_t)(a0 + 0) * 8] = h0;
    Uhi[base + (size_t)(a0 + 1) * 8] = h1;
    Uhi[base + (size_t)(a0 + 2) * 8] = h2;
    Ulo[base + (size_t)(a0 + 0) * 8] = (_Float16)(v0 - (float)h0);
    Ulo[base + (size_t)(a0 + 1) * 8] = (_Float16)(v1 - (float)h1);
    Ulo[base + (size_t)(a0 + 2) * 8] = (_Float16)(v2 - (float)h2);
  }
  __shared__ float wss[3][4];
  const int wid = t >> 6, lane = t & 63;
  float s[3] = {ss0, ss1, ss2};
#pragma unroll
  for (int kw = 0; kw < 3; ++kw) {
    float v = s[kw];
#pragma unroll
    for (int off = 32; off > 0; off >>= 1) v += __shfl_down(v, off, 64);
    if (lane == 0) wss[kw][wid] = v;
  }
  __syncthreads();
  if (t < 3) {
    const float tot = wss[t][0] + wss[t][1] + wss[t][2] + wss[t][3];
    nrecip[a0 + t] = 1.0f / sqrtf(tot);
  }
}

// ---------------------------------------------------------------------------
// Pass 2: D[i,j] = sty_i . img_j, 3-term f16 split, 32x32x16 MFMA, 128x128
// tile, DOUBLE-BUFFERED LDS with raw s_barrier + s_waitcnt vmcnt(8):
// prefetch stage k+1 issues before compute of stage k; the wait covers only
// the PREVIOUS stage's 8 GLDS (a full compute-phase of slack). No
// __syncthreads in the loop => no compiler vmcnt(0) drain (the m97 stall).
// ---------------------------------------------------------------------------
#define GLDS(g, l)                                                          \
  __builtin_amdgcn_global_load_lds(                                        \
      (const __attribute__((address_space(1))) void*)(g),                   \
      (__attribute__((address_space(3))) void*)(l), 16, 0, 0)

__global__ __launch_bounds__(256, 2) void gemm_max_kernel(
    const _Float16* __restrict__ Shi, const _Float16* __restrict__ Slo,
    const _Float16* __restrict__ Ihi, const _Float16* __restrict__ Ilo,
    const float* __restrict__ img_nr,
    unsigned long long* __restrict__ packed) {
  // sm[buf][mat][ (kchunk*128 + row)*8 ], mat: 0=Ah 1=Al 2=Bh 3=Bl. 64 KB.
  __shared__ _Float16 sm[2][4][4 * 128 * 8];

  const int t = threadIdx.x;
  const int lane = t & 63, wv = t >> 6;
  const int wvr = wv >> 1, wvc = wv & 1;       // 2x2 waves, wave tile 64x64
  const int row0 = blockIdx.y * BM;            // sty rows (i)
  const int col0 = blockIdx.x * BN;            // img rows (j)
  const int l31 = lane & 31, hs = lane >> 5;

  floatx16 acc[2][2];
#pragma unroll
  for (int rf = 0; rf < 2; ++rf)
#pragma unroll
    for (int cf = 0; cf < 2; ++cf) acc[rf][cf] = (floatx16)0.f;

  // Staging: thread t covers (plane = t>>7, row = t&127); two GLDS per matrix
  // (planes +0, +2). LDS dest = t*16B (wave-uniform base + lane*16, legal).
  const size_t CH8 = (size_t)A_DIM * 8;        // one kchunk plane, in halves
  const size_t so = (size_t)(t & 127) * 8 + (size_t)(t >> 7) * CH8;
  const _Float16* __restrict__ pAh = Shi + (size_t)row0 * 8 + so;
  const _Float16* __restrict__ pAl = Slo + (size_t)row0 * 8 + so;
  const _Float16* __restrict__ pBh = Ihi + (size_t)col0 * 8 + so;
  const _Float16* __restrict__ pBl = Ilo + (size_t)col0 * 8 + so;
  const int dl = t * 8;  // halves == t*16 bytes

#define ISSUE(b, off)                                      \
  do {                                                     \
    GLDS(pAh + (off),           &sm[b][0][dl]);            \
    GLDS(pAh + (off) + 2 * CH8, &sm[b][0][dl + 2048]);     \
    GLDS(pAl + (off),           &sm[b][1][dl]);            \
    GLDS(pAl + (off) + 2 * CH8, &sm[b][1][dl + 2048]);     \
    GLDS(pBh + (off),           &sm[b][2][dl]);            \
    GLDS(pBh + (off) + 2 * CH8, &sm[b][2][dl + 2048]);     \
    GLDS(pBl + (off),           &sm[b][3][dl]);            \
    GLDS(pBl + (off) + 2 * CH8, &sm[b][3][dl + 2048]);     \
  } while (0)

  ISSUE(0, 0);  // prologue prefetch of stage 0

  for (int ks = 0; ks < NS; ++ks) {
    const int cur = ks & 1;
    if (ks + 1 < NS) {
      ISSUE(1 - cur, (size_t)(ks + 1) * 4 * CH8);
      asm volatile("s_waitcnt vmcnt(8)" ::: "memory");  // stage ks complete
    } else {
      asm volatile("s_waitcnt vmcnt(0)" ::: "memory");
    }
    asm volatile("s_barrier" ::: "memory");  // all waves' stage-ks data in LDS

#pragma unroll
    for (int kk = 0; kk < 2; ++kk) {
      const int kc = kk * 2 + hs;  // kchunk this lane-half consumes
      half8 ah[2], al[2], bh[2], bl[2];
#pragma unroll
      for (int rf = 0; rf < 2; ++rf) {
        const int idx = (kc * 128 + wvr * 64 + rf * 32 + l31) * 8;
        ah[rf] = *(const half8*)&sm[cur][0][idx];
        al[rf] = *(const half8*)&sm[cur][1][idx];
      }
#pragma unroll
      for (int cf = 0; cf < 2; ++cf) {
        const int idx = (kc * 128 + wvc * 64 + cf * 32 + l31) * 8;
        bh[cf] = *(const half8*)&sm[cur][2][idx];
        bl[cf] = *(const half8*)&sm[cur][3][idx];
      }
      // term-major order: same acc reused every 4 MFMAs (pipe-latency safe)
#pragma unroll
      for (int rf = 0; rf < 2; ++rf)
#pragma unroll
        for (int cf = 0; cf < 2; ++cf)
          acc[rf][cf] = __builtin_amdgcn_mfma_f32_32x32x16_f16(
              ah[rf], bh[cf], acc[rf][cf], 0, 0, 0);
#pragma unroll
      for (int rf = 0; rf < 2; ++rf)
#pragma unroll
        for (int cf = 0; cf < 2; ++cf)
          acc[rf][cf] = __builtin_amdgcn_mfma_f32_32x32x16_f16(
              ah[rf], bl[cf], acc[rf][cf], 0, 0, 0);
#pragma unroll
      for (int rf = 0; rf < 2; ++rf)
#pragma unroll
        for (int cf = 0; cf < 2; ++cf)
          acc[rf][cf] = __builtin_amdgcn_mfma_f32_32x32x16_f16(
              al[rf], bh[cf], acc[rf][cf], 0, 0, 0);
    }
    asm volatile("s_barrier" ::: "memory");  // reads done before overwrite
  }

  // Epilogue: v[i,j] = img_nr[i]*D[i,j]; column max+argmax (first-index wins).
  // 32x32 C/D layout: col = lane&31, row = (reg&3) + 8*(reg>>2) + 4*(lane>>5).
#pragma unroll
  for (int cf = 0; cf < 2; ++cf) {
    const int j = col0 + wvc * 64 + cf * 32 + l31;
    float best = -3.4e38f;
    int bi = 0x7FFFFFFF;
#pragma unroll
    for (int rf = 0; rf < 2; ++rf) {
      const int base_i = row0 + wvr * 64 + rf * 32 + 4 * hs;
#pragma unroll
      for (int g = 0; g < 4; ++g) {
        const floatx4 n4 = *(const floatx4*)&img_nr[base_i + 8 * g];
#pragma unroll
        for (int r = 0; r < 4; ++r) {
          const int i = base_i + 8 * g + r;
          const float v = acc[rf][cf][g * 4 + r] * n4[r];
          if (v > best) { best = v; bi = i; }  // ascending i => first wins
        }
      }
    }
    const float ov = __shfl_xor(best, 32, 64);
    const int oi = __shfl_xor(bi, 32, 64);
    if (ov > best || (ov == best && oi < bi)) { best = ov; bi = oi; }
    if (hs == 0) {
      const unsigned u = __float_as_uint(best);
      const unsigned key = (u & 0x80000000u) ? ~u : (u | 0x80000000u);
      const unsigned long long pk =
          ((unsigned long long)key << 32) | (unsigned)(~(unsigned)bi);
      atomicMax(&packed[j], pk);
    }
  }
}

// ---------------------------------------------------------------------------
// Pass 3: decode packed, apply sty_nr[j]; out[0..A)=nearest, out[A..2A)=max.
// ---------------------------------------------------------------------------
__global__ __launch_bounds__(256) void finalize_kernel(
    const unsigned long long* __restrict__ packed,
    const float* __restrict__ sty_nr, float* __restrict__ out) {
  const int j = blockIdx.x * 256 + threadIdx.x;
  if (j >= A_DIM) return;
  const unsigned long long p = packed[j];
  const unsigned key = (unsigned)(p >> 32);
  const unsigned u = (key & 0x80000000u) ? (key ^ 0x80000000u) : ~key;
  const float v = __uint_as_float(u);
  const int idx = (int)(~(unsigned)(p & 0xFFFFFFFFu));
  out[j] = (float)idx;
  out[A_DIM + j] = v * sty_nr[j];
}

extern "C" void kernel_launch(void* const* d_in, const int* in_sizes, int n_in,
                              void* d_out, int out_size, void* d_ws, size_t ws_size,
                              hipStream_t stream) {
  const float* model = (const float*)d_in[0];  // img side
  const float* style = (const float*)d_in[1];  // sty side
  float* out = (float*)d_out;
  char* ws = (char*)d_ws;

  const size_t usz = (size_t)A_DIM * L_DIM * 2;  // one f16 matrix: 37,748,736 B
  _Float16* img_hi = (_Float16*)(ws);
  _Float16* img_lo = (_Float16*)(ws + usz);
  _Float16* sty_hi = (_Float16*)(ws + 2 * usz);
  _Float16* sty_lo = (_Float16*)(ws + 3 * usz);
  float* img_nr = (float*)(ws + 4 * usz);
  float* sty_nr = img_nr + A_DIM;
  unsigned long long* packed = (unsigned long long*)(img_nr + 2 * A_DIM);

  hipMemsetAsync(packed, 0, (size_t)A_DIM * 8, stream);
  prep_kernel<<<dim3(CH, 3, 2), 256, 0, stream>>>(
      model, style, img_hi, img_lo, sty_hi, sty_lo, img_nr, sty_nr);
  gemm_max_kernel<<<dim3(A_DIM / BN, A_DIM / BM), 256, 0, stream>>>(
      sty_hi, sty_lo, img_hi, img_lo, img_nr, packed);
  finalize_kernel<<<18, 256, 0, stream>>>(packed, sty_nr, out);
}

// Round 7
// 743.870 us; speedup vs baseline: 1.2169x; 1.0730x over previous
//
#include <hip/hip_runtime.h>
#include <hip/hip_bf16.h>
#include <hip/hip_fp16.h>

// Problem dims
#define A_DIM 4608   // C*9 patch-feature rows
#define L_DIM 4096   // (H/3)*(W/3) spatial columns
#define CH    512
#define H_DIM 192
#define W_DIM 192

// GEMM tile
#define BM 128
#define BN 128
#define BK 32        // 4 kchunks of 8 halves per stage
#define NS (L_DIM / BK)

#define CPB 32       // prep: channels per block

typedef _Float16 half8 __attribute__((ext_vector_type(8)));
typedef float   floatx4 __attribute__((ext_vector_type(4)));
typedef float   floatx16 __attribute__((ext_vector_type(16)));

// ---------------------------------------------------------------------------
// Pass 1: unfold(x) -> k-chunk-major f16 hi/lo split + GLOBAL sum-of-squares
// accumulation (ss arrays are pre-zeroed; each block atomicAdds its partial —
// fixes the R6 cross-block norm race).
// Global layout: U[(l>>3)*A_DIM + a][8] (chunk-major; GEMM staging contiguous
// and conflict-free — verified R4/R5: GEMM SQ_LDS_BANK_CONFLICT = 0).
// Block = (32 channels, one ph, one input). Thread s=t&7 reads 24-float runs
// (coalesced within L1-resident 768B windows) and owns complete 16B output
// chunks (c8 = ph*8+s) in registers; LDS (XOR-swizzled) turns the scatter
// into fully-coalesced 16B global writes in phase 2.
// ---------------------------------------------------------------------------
__global__ __launch_bounds__(256) void prep_kernel(
    const float* __restrict__ x0, const float* __restrict__ x1,
    _Float16* __restrict__ Uhi0, _Float16* __restrict__ Ulo0,
    _Float16* __restrict__ Uhi1, _Float16* __restrict__ Ulo1,
    float* __restrict__ ss0, float* __restrict__ ss1) {
  const int which = blockIdx.z;
  const float* __restrict__ x = which ? x1 : x0;
  _Float16* __restrict__ Uhi = which ? Uhi1 : Uhi0;
  _Float16* __restrict__ Ulo = which ? Ulo1 : Ulo0;
  float* __restrict__ ssg = which ? ss1 : ss0;

  const int ph = blockIdx.y;            // 0..63
  const int c0 = blockIdx.x * CPB;      // channel group base
  const int abase = blockIdx.x * (CPB * 9);

  __shared__ _Float16 sHi[CPB * 9 * 8 * 8];  // 288 rows x 8 chunks x 8 halves
  __shared__ _Float16 sLo[CPB * 9 * 8 * 8];
  __shared__ float ssb[CPB * 9];

  const int t = threadIdx.x;
  for (int a = t; a < CPB * 9; a += 256) ssb[a] = 0.f;
  __syncthreads();

  // ---- phase 1: read input coalesced, assemble chunks in regs, stage in LDS
  const int c_l = t >> 3;               // 0..31
  const int s = t & 7;                  // chunk index this thread owns
  const float* __restrict__ rowbase =
      x + ((size_t)(c0 + c_l) * H_DIM + 3 * ph) * W_DIM + s * 24;
  float ssp[9] = {0.f, 0.f, 0.f, 0.f, 0.f, 0.f, 0.f, 0.f, 0.f};

#pragma unroll
  for (int kh = 0; kh < 3; ++kh) {
    const float* __restrict__ rp = rowbase + kh * W_DIM;
    floatx4 v4[6];
#pragma unroll
    for (int i = 0; i < 6; ++i) v4[i] = *(const floatx4*)(rp + i * 4);
    half8 hv[3], lv[3];
#pragma unroll
    for (int i = 0; i < 6; ++i)
#pragma unroll
      for (int j = 0; j < 4; ++j) {
        const int m = i * 4 + j;        // 0..23
        const int kw = m % 3, e = m / 3;
        const float v = v4[i][j];
        ssp[kh * 3 + kw] += v * v;
        const _Float16 h = (_Float16)v;
        hv[kw][e] = h;
        lv[kw][e] = (_Float16)(v - (float)h);
      }
#pragma unroll
    for (int kw = 0; kw < 3; ++kw) {
      const int a_l = c_l * 9 + kh * 3 + kw;
      const int addr = (a_l * 8 + (s ^ (a_l & 7))) * 8;  // XOR-swizzled chunk
      *(half8*)&sHi[addr] = hv[kw];
      *(half8*)&sLo[addr] = lv[kw];
    }
  }
#pragma unroll
  for (int q = 0; q < 9; ++q) atomicAdd(&ssb[c_l * 9 + q], ssp[q]);
  __syncthreads();

  // ---- phase 2: coalesced global writes (consecutive t = consecutive a)
#pragma unroll
  for (int i = 0; i < 9; ++i) {
    const int idx = i * 256 + t;        // 0..2303
    const int c8 = idx / 288;
    const int a_l = idx - c8 * 288;
    const int addr = (a_l * 8 + (c8 ^ (a_l & 7))) * 8;
    const size_t g = ((size_t)(ph * 8 + c8) * A_DIM + abase + a_l) * 8;
    *(half8*)&Uhi[g] = *(const half8*)&sHi[addr];
    *(half8*)&Ulo[g] = *(const half8*)&sLo[addr];
  }
  // ---- global norm accumulation (cross-block over ph)
  for (int a = t; a < CPB * 9; a += 256) atomicAdd(&ssg[abase + a], ssb[a]);
}

// ---------------------------------------------------------------------------
// Pass 2: D[i,j] = sty_i . img_j, 3-term f16 split, 32x32x16 MFMA, 128x128
// tile, double-buffered LDS, ONE barrier per stage:
//   vmcnt(0) [own stage-ks GLDS done] -> s_barrier [all waves done; all waves'
//   reads of the other buffer retired into VGPRs pre-barrier via MFMA operand
//   lgkm waits] -> ISSUE(ks+1 -> other buffer) -> compute(cur).
// Epilogue computes img row rsqrt inline from the global ss accumulator.
// ---------------------------------------------------------------------------
#define GLDS(g, l)                                                          \
  __builtin_amdgcn_global_load_lds(                                        \
      (const __attribute__((address_space(1))) void*)(g),                   \
      (__attribute__((address_space(3))) void*)(l), 16, 0, 0)

__global__ __launch_bounds__(256, 2) void gemm_max_kernel(
    const _Float16* __restrict__ Shi, const _Float16* __restrict__ Slo,
    const _Float16* __restrict__ Ihi, const _Float16* __restrict__ Ilo,
    const float* __restrict__ img_ss,
    unsigned long long* __restrict__ packed) {
  // sm[buf][mat][ (kchunk*128 + row)*8 ], mat: 0=Ah 1=Al 2=Bh 3=Bl. 64 KB.
  __shared__ _Float16 sm[2][4][4 * 128 * 8];

  const int t = threadIdx.x;
  const int lane = t & 63, wv = t >> 6;
  const int wvr = wv >> 1, wvc = wv & 1;       // 2x2 waves, wave tile 64x64
  const int row0 = blockIdx.y * BM;            // sty rows (i)
  const int col0 = blockIdx.x * BN;            // img rows (j)
  const int l31 = lane & 31, hs = lane >> 5;

  floatx16 acc[2][2];
#pragma unroll
  for (int rf = 0; rf < 2; ++rf)
#pragma unroll
    for (int cf = 0; cf < 2; ++cf) acc[rf][cf] = (floatx16)0.f;

  // Staging: thread t covers (plane = t>>7, row = t&127); two GLDS per matrix
  // (planes +0, +2). LDS dest = t*16B (wave-uniform base + lane*16, legal).
  const size_t CH8 = (size_t)A_DIM * 8;        // one kchunk plane, in halves
  const size_t so = (size_t)(t & 127) * 8 + (size_t)(t >> 7) * CH8;
  const _Float16* __restrict__ pAh = Shi + (size_t)row0 * 8 + so;
  const _Float16* __restrict__ pAl = Slo + (size_t)row0 * 8 + so;
  const _Float16* __restrict__ pBh = Ihi + (size_t)col0 * 8 + so;
  const _Float16* __restrict__ pBl = Ilo + (size_t)col0 * 8 + so;
  const int dl = t * 8;  // halves == t*16 bytes

#define ISSUE(b, off)                                      \
  do {                                                     \
    GLDS(pAh + (off),           &sm[b][0][dl]);            \
    GLDS(pAh + (off) + 2 * CH8, &sm[b][0][dl + 2048]);     \
    GLDS(pAl + (off),           &sm[b][1][dl]);            \
    GLDS(pAl + (off) + 2 * CH8, &sm[b][1][dl + 2048]);     \
    GLDS(pBh + (off),           &sm[b][2][dl]);            \
    GLDS(pBh + (off) + 2 * CH8, &sm[b][2][dl + 2048]);     \
    GLDS(pBl + (off),           &sm[b][3][dl]);            \
    GLDS(pBl + (off) + 2 * CH8, &sm[b][3][dl + 2048]);     \
  } while (0)

  ISSUE(0, 0);  // prologue prefetch of stage 0

  for (int ks = 0; ks < NS; ++ks) {
    const int cur = ks & 1;
    asm volatile("s_waitcnt vmcnt(0)" ::: "memory");  // own stage-ks GLDS done
    asm volatile("s_barrier" ::: "memory");           // everyone's done
    if (ks + 1 < NS) ISSUE(1 - cur, (size_t)(ks + 1) * 4 * CH8);

#pragma unroll
    for (int kk = 0; kk < 2; ++kk) {
      const int kc = kk * 2 + hs;  // kchunk this lane-half consumes
      half8 ah[2], al[2], bh[2], bl[2];
#pragma unroll
      for (int rf = 0; rf < 2; ++rf) {
        const int idx = (kc * 128 + wvr * 64 + rf * 32 + l31) * 8;
        ah[rf] = *(const half8*)&sm[cur][0][idx];
        al[rf] = *(const half8*)&sm[cur][1][idx];
      }
#pragma unroll
      for (int cf = 0; cf < 2; ++cf) {
        const int idx = (kc * 128 + wvc * 64 + cf * 32 + l31) * 8;
        bh[cf] = *(const half8*)&sm[cur][2][idx];
        bl[cf] = *(const half8*)&sm[cur][3][idx];
      }
      // term-major order: same acc reused every 4 MFMAs (pipe-latency safe)
#pragma unroll
      for (int rf = 0; rf < 2; ++rf)
#pragma unroll
        for (int cf = 0; cf < 2; ++cf)
          acc[rf][cf] = __builtin_amdgcn_mfma_f32_32x32x16_f16(
              ah[rf], bh[cf], acc[rf][cf], 0, 0, 0);
#pragma unroll
      for (int rf = 0; rf < 2; ++rf)
#pragma unroll
        for (int cf = 0; cf < 2; ++cf)
          acc[rf][cf] = __builtin_amdgcn_mfma_f32_32x32x16_f16(
              ah[rf], bl[cf], acc[rf][cf], 0, 0, 0);
#pragma unroll
      for (int rf = 0; rf < 2; ++rf)
#pragma unroll
        for (int cf = 0; cf < 2; ++cf)
          acc[rf][cf] = __builtin_amdgcn_mfma_f32_32x32x16_f16(
              al[rf], bh[cf], acc[rf][cf], 0, 0, 0);
    }
  }

  // Epilogue: v[i,j] = rsqrt(img_ss[i]) * D[i,j]; column max+argmax
  // (first-index wins). 32x32 C/D: col=lane&31, row=(reg&3)+8*(reg>>2)+4*hs.
  float nrv[2][16];
#pragma unroll
  for (int rf = 0; rf < 2; ++rf) {
    const int base_i = row0 + wvr * 64 + rf * 32 + 4 * hs;
#pragma unroll
    for (int g = 0; g < 4; ++g) {
      const floatx4 s4 = *(const floatx4*)&img_ss[base_i + 8 * g];
#pragma unroll
      for (int r = 0; r < 4; ++r) nrv[rf][g * 4 + r] = 1.0f / sqrtf(s4[r]);
    }
  }
#pragma unroll
  for (int cf = 0; cf < 2; ++cf) {
    const int j = col0 + wvc * 64 + cf * 32 + l31;
    float best = -3.4e38f;
    int bi = 0x7FFFFFFF;
#pragma unroll
    for (int rf = 0; rf < 2; ++rf) {
      const int base_i = row0 + wvr * 64 + rf * 32 + 4 * hs;
#pragma unroll
      for (int g = 0; g < 4; ++g)
#pragma unroll
        for (int r = 0; r < 4; ++r) {
          const int i = base_i + 8 * g + r;
          const float v = acc[rf][cf][g * 4 + r] * nrv[rf][g * 4 + r];
          if (v > best) { best = v; bi = i; }  // ascending i => first wins
        }
    }
    const float ov = __shfl_xor(best, 32, 64);
    const int oi = __shfl_xor(bi, 32, 64);
    if (ov > best || (ov == best && oi < bi)) { best = ov; bi = oi; }
    if (hs == 0) {
      const unsigned u = __float_as_uint(best);
      const unsigned key = (u & 0x80000000u) ? ~u : (u | 0x80000000u);
      const unsigned long long pk =
          ((unsigned long long)key << 32) | (unsigned)(~(unsigned)bi);
      atomicMax(&packed[j], pk);
    }
  }
}

// ---------------------------------------------------------------------------
// Pass 3: decode packed, apply rsqrt(sty_ss[j]); out[0..A)=nearest,
// out[A..2A)=max_sim.
// ---------------------------------------------------------------------------
__global__ __launch_bounds__(256) void finalize_kernel(
    const unsigned long long* __restrict__ packed,
    const float* __restrict__ sty_ss, float* __restrict__ out) {
  const int j = blockIdx.x * 256 + threadIdx.x;
  if (j >= A_DIM) return;
  const unsigned long long p = packed[j];
  const unsigned key = (unsigned)(p >> 32);
  const unsigned u = (key & 0x80000000u) ? (key ^ 0x80000000u) : ~key;
  const float v = __uint_as_float(u);
  const int idx = (int)(~(unsigned)(p & 0xFFFFFFFFu));
  out[j] = (float)idx;
  out[A_DIM + j] = v * (1.0f / sqrtf(sty_ss[j]));
}

extern "C" void kernel_launch(void* const* d_in, const int* in_sizes, int n_in,
                              void* d_out, int out_size, void* d_ws, size_t ws_size,
                              hipStream_t stream) {
  const float* model = (const float*)d_in[0];  // img side
  const float* style = (const float*)d_in[1];  // sty side
  float* out = (float*)d_out;
  char* ws = (char*)d_ws;

  const size_t usz = (size_t)A_DIM * L_DIM * 2;  // one f16 matrix: 37,748,736 B
  _Float16* img_hi = (_Float16*)(ws);
  _Float16* img_lo = (_Float16*)(ws + usz);
  _Float16* sty_hi = (_Float16*)(ws + 2 * usz);
  _Float16* sty_lo = (_Float16*)(ws + 3 * usz);
  float* img_ss = (float*)(ws + 4 * usz);        // zeroed accumulators
  float* sty_ss = img_ss + A_DIM;
  unsigned long long* packed = (unsigned long long*)(img_ss + 2 * A_DIM);

  // zero ss accumulators (2*A*4 B) + packed (A*8 B) in one contiguous memset
  hipMemsetAsync(img_ss, 0, (size_t)A_DIM * 16, stream);
  prep_kernel<<<dim3(CH / CPB, H_DIM / 3, 2), 256, 0, stream>>>(
      model, style, img_hi, img_lo, sty_hi, sty_lo, img_ss, sty_ss);
  gemm_max_kernel<<<dim3(A_DIM / BN, A_DIM / BM), 256, 0, stream>>>(
      sty_hi, sty_lo, img_hi, img_lo, img_ss, packed);
  finalize_kernel<<<18, 256, 0, stream>>>(packed, sty_ss, out);
}

// Round 8
// 729.920 us; speedup vs baseline: 1.2401x; 1.0191x over previous
//
#include <hip/hip_runtime.h>
#include <hip/hip_bf16.h>
#include <hip/hip_fp16.h>

// Problem dims
#define A_DIM 4608   // C*9 patch-feature rows
#define L_DIM 4096   // (H/3)*(W/3) spatial columns
#define CH    512
#define H_DIM 192
#define W_DIM 192

// GEMM tile
#define BM 128
#define BN 128
#define BK 32        // 4 kchunks of 8 halves per stage
#define NS (L_DIM / BK)

#define CPB 32       // prep: channels per block

typedef _Float16 half8 __attribute__((ext_vector_type(8)));
typedef float   floatx4 __attribute__((ext_vector_type(4)));
typedef float   floatx16 __attribute__((ext_vector_type(16)));

// ---------------------------------------------------------------------------
// Pass 1: unfold(x) -> k-chunk-major f16 hi/lo split + global sum-of-squares
// accumulation (ss arrays pre-zeroed; block atomicAdds its partials).
// Global layout: U[(l>>3)*A_DIM + a][8] (chunk-major; GEMM staging contiguous
// and conflict-free — verified R4/R5/R7: GEMM SQ_LDS_BANK_CONFLICT = 0).
// ---------------------------------------------------------------------------
__global__ __launch_bounds__(256) void prep_kernel(
    const float* __restrict__ x0, const float* __restrict__ x1,
    _Float16* __restrict__ Uhi0, _Float16* __restrict__ Ulo0,
    _Float16* __restrict__ Uhi1, _Float16* __restrict__ Ulo1,
    float* __restrict__ ss0, float* __restrict__ ss1) {
  const int which = blockIdx.z;
  const float* __restrict__ x = which ? x1 : x0;
  _Float16* __restrict__ Uhi = which ? Uhi1 : Uhi0;
  _Float16* __restrict__ Ulo = which ? Ulo1 : Ulo0;
  float* __restrict__ ssg = which ? ss1 : ss0;

  const int ph = blockIdx.y;            // 0..63
  const int c0 = blockIdx.x * CPB;      // channel group base
  const int abase = blockIdx.x * (CPB * 9);

  __shared__ _Float16 sHi[CPB * 9 * 8 * 8];  // 288 rows x 8 chunks x 8 halves
  __shared__ _Float16 sLo[CPB * 9 * 8 * 8];
  __shared__ float ssb[CPB * 9];

  const int t = threadIdx.x;
  for (int a = t; a < CPB * 9; a += 256) ssb[a] = 0.f;
  __syncthreads();

  // ---- phase 1: read input, assemble 16B chunks in regs, stage in LDS
  const int c_l = t >> 3;               // 0..31
  const int s = t & 7;                  // chunk index this thread owns
  const float* __restrict__ rowbase =
      x + ((size_t)(c0 + c_l) * H_DIM + 3 * ph) * W_DIM + s * 24;
  float ssp[9] = {0.f, 0.f, 0.f, 0.f, 0.f, 0.f, 0.f, 0.f, 0.f};

#pragma unroll
  for (int kh = 0; kh < 3; ++kh) {
    const float* __restrict__ rp = rowbase + kh * W_DIM;
    floatx4 v4[6];
#pragma unroll
    for (int i = 0; i < 6; ++i) v4[i] = *(const floatx4*)(rp + i * 4);
    half8 hv[3], lv[3];
#pragma unroll
    for (int i = 0; i < 6; ++i)
#pragma unroll
      for (int j = 0; j < 4; ++j) {
        const int m = i * 4 + j;        // 0..23
        const int kw = m % 3, e = m / 3;
        const float v = v4[i][j];
        ssp[kh * 3 + kw] += v * v;
        const _Float16 h = (_Float16)v;
        hv[kw][e] = h;
        lv[kw][e] = (_Float16)(v - (float)h);
      }
#pragma unroll
    for (int kw = 0; kw < 3; ++kw) {
      const int a_l = c_l * 9 + kh * 3 + kw;
      const int addr = (a_l * 8 + (s ^ (a_l & 7))) * 8;  // XOR-swizzled chunk
      *(half8*)&sHi[addr] = hv[kw];
      *(half8*)&sLo[addr] = lv[kw];
    }
  }
#pragma unroll
  for (int q = 0; q < 9; ++q) atomicAdd(&ssb[c_l * 9 + q], ssp[q]);
  __syncthreads();

  // ---- phase 2: coalesced global writes (consecutive t = consecutive a)
#pragma unroll
  for (int i = 0; i < 9; ++i) {
    const int idx = i * 256 + t;        // 0..2303
    const int c8 = idx / 288;
    const int a_l = idx - c8 * 288;
    const int addr = (a_l * 8 + (c8 ^ (a_l & 7))) * 8;
    const size_t g = ((size_t)(ph * 8 + c8) * A_DIM + abase + a_l) * 8;
    *(half8*)&Uhi[g] = *(const half8*)&sHi[addr];
    *(half8*)&Ulo[g] = *(const half8*)&sLo[addr];
  }
  // ---- global norm accumulation (cross-block over ph)
  for (int a = t; a < CPB * 9; a += 256) atomicAdd(&ssg[abase + a], ssb[a]);
}

// ---------------------------------------------------------------------------
// Pass 2: D[i,j] = sty_i . img_j, 3-term f16 split, 32x32x16 MFMA, 128x128
// tile, double-buffered LDS with the R5-proven loop order:
//   ISSUE(ks+1) -> s_waitcnt vmcnt(8) [stage ks complete, ks+1 stays in
//   flight across the barrier] -> s_barrier -> compute -> s_barrier.
// (R7 lesson: wait-then-barrier with vmcnt(0) drains the VMEM queue at every
// barrier and costs ~7%; never cross the barrier with an empty queue.)
//
// Block swizzle (1-D grid): id -> (bx,by) such that XCD (heuristic id%8)
// pins one B col-tile (2 MB, fits 4 MB XCD-L2) across all 36 by-steps,
// cutting L2-miss/L3 read traffic roughly in half.
// ---------------------------------------------------------------------------
#define GLDS(g, l)                                                          \
  __builtin_amdgcn_global_load_lds(                                        \
      (const __attribute__((address_space(1))) void*)(g),                   \
      (__attribute__((address_space(3))) void*)(l), 16, 0, 0)

__global__ __launch_bounds__(256, 2) void gemm_max_kernel(
    const _Float16* __restrict__ Shi, const _Float16* __restrict__ Slo,
    const _Float16* __restrict__ Ihi, const _Float16* __restrict__ Ilo,
    const float* __restrict__ img_ss,
    unsigned long long* __restrict__ packed) {
  // sm[buf][mat][ (kchunk*128 + row)*8 ], mat: 0=Ah 1=Al 2=Bh 3=Bl. 64 KB.
  __shared__ _Float16 sm[2][4][4 * 128 * 8];

  const int t = threadIdx.x;
  const int lane = t & 63, wv = t >> 6;
  const int wvr = wv >> 1, wvc = wv & 1;       // 2x2 waves, wave tile 64x64
  // swizzled block mapping: groups of 8 columns; within a group, consecutive
  // linear ids step `by` with bx_lo (=XCD slot) fixed.
  const int id = blockIdx.x;
  int bx, by;
  if (id < 1152) {
    const int g = id / 288, r = id - g * 288;
    by = r >> 3; bx = g * 8 + (r & 7);
  } else {
    const int r = id - 1152;
    by = r >> 2; bx = 32 + (r & 3);
  }
  const int row0 = by * BM;                    // sty rows (i)
  const int col0 = bx * BN;                    // img rows (j)
  const int l31 = lane & 31, hs = lane >> 5;

  floatx16 acc[2][2];
#pragma unroll
  for (int rf = 0; rf < 2; ++rf)
#pragma unroll
    for (int cf = 0; cf < 2; ++cf) acc[rf][cf] = (floatx16)0.f;

  // Staging: thread t covers (plane = t>>7, row = t&127); two GLDS per matrix
  // (planes +0, +2). LDS dest = t*16B (wave-uniform base + lane*16, legal).
  const size_t CH8 = (size_t)A_DIM * 8;        // one kchunk plane, in halves
  const size_t so = (size_t)(t & 127) * 8 + (size_t)(t >> 7) * CH8;
  const _Float16* __restrict__ pAh = Shi + (size_t)row0 * 8 + so;
  const _Float16* __restrict__ pAl = Slo + (size_t)row0 * 8 + so;
  const _Float16* __restrict__ pBh = Ihi + (size_t)col0 * 8 + so;
  const _Float16* __restrict__ pBl = Ilo + (size_t)col0 * 8 + so;
  const int dl = t * 8;  // halves == t*16 bytes

#define ISSUE(b, off)                                      \
  do {                                                     \
    GLDS(pAh + (off),           &sm[b][0][dl]);            \
    GLDS(pAh + (off) + 2 * CH8, &sm[b][0][dl + 2048]);     \
    GLDS(pAl + (off),           &sm[b][1][dl]);            \
    GLDS(pAl + (off) + 2 * CH8, &sm[b][1][dl + 2048]);     \
    GLDS(pBh + (off),           &sm[b][2][dl]);            \
    GLDS(pBh + (off) + 2 * CH8, &sm[b][2][dl + 2048]);     \
    GLDS(pBl + (off),           &sm[b][3][dl]);            \
    GLDS(pBl + (off) + 2 * CH8, &sm[b][3][dl + 2048]);     \
  } while (0)

  ISSUE(0, 0);  // prologue prefetch of stage 0

  for (int ks = 0; ks < NS; ++ks) {
    const int cur = ks & 1;
    if (ks + 1 < NS) {
      ISSUE(1 - cur, (size_t)(ks + 1) * 4 * CH8);
      asm volatile("s_waitcnt vmcnt(8)" ::: "memory");  // stage ks complete
    } else {
      asm volatile("s_waitcnt vmcnt(0)" ::: "memory");
    }
    asm volatile("s_barrier" ::: "memory");  // all waves' stage-ks data in LDS

#pragma unroll
    for (int kk = 0; kk < 2; ++kk) {
      const int kc = kk * 2 + hs;  // kchunk this lane-half consumes
      half8 ah[2], al[2], bh[2], bl[2];
#pragma unroll
      for (int rf = 0; rf < 2; ++rf) {
        const int idx = (kc * 128 + wvr * 64 + rf * 32 + l31) * 8;
        ah[rf] = *(const half8*)&sm[cur][0][idx];
        al[rf] = *(const half8*)&sm[cur][1][idx];
      }
#pragma unroll
      for (int cf = 0; cf < 2; ++cf) {
        const int idx = (kc * 128 + wvc * 64 + cf * 32 + l31) * 8;
        bh[cf] = *(const half8*)&sm[cur][2][idx];
        bl[cf] = *(const half8*)&sm[cur][3][idx];
      }
      // term-major order: same acc reused every 4 MFMAs (pipe-latency safe)
#pragma unroll
      for (int rf = 0; rf < 2; ++rf)
#pragma unroll
        for (int cf = 0; cf < 2; ++cf)
          acc[rf][cf] = __builtin_amdgcn_mfma_f32_32x32x16_f16(
              ah[rf], bh[cf], acc[rf][cf], 0, 0, 0);
#pragma unroll
      for (int rf = 0; rf < 2; ++rf)
#pragma unroll
        for (int cf = 0; cf < 2; ++cf)
          acc[rf][cf] = __builtin_amdgcn_mfma_f32_32x32x16_f16(
              ah[rf], bl[cf], acc[rf][cf], 0, 0, 0);
#pragma unroll
      for (int rf = 0; rf < 2; ++rf)
#pragma unroll
        for (int cf = 0; cf < 2; ++cf)
          acc[rf][cf] = __builtin_amdgcn_mfma_f32_32x32x16_f16(
              al[rf], bh[cf], acc[rf][cf], 0, 0, 0);
    }
    asm volatile("s_barrier" ::: "memory");  // reads done before overwrite
  }

  // Epilogue: v[i,j] = rsqrt(img_ss[i]) * D[i,j]; column max+argmax
  // (first-index wins). 32x32 C/D: col=lane&31, row=(reg&3)+8*(reg>>2)+4*hs.
  float nrv[2][16];
#pragma unroll
  for (int rf = 0; rf < 2; ++rf) {
    const int base_i = row0 + wvr * 64 + rf * 32 + 4 * hs;
#pragma unroll
    for (int g = 0; g < 4; ++g) {
      const floatx4 s4 = *(const floatx4*)&img_ss[base_i + 8 * g];
#pragma unroll
      for (int r = 0; r < 4; ++r) nrv[rf][g * 4 + r] = 1.0f / sqrtf(s4[r]);
    }
  }
#pragma unroll
  for (int cf = 0; cf < 2; ++cf) {
    const int j = col0 + wvc * 64 + cf * 32 + l31;
    float best = -3.4e38f;
    int bi = 0x7FFFFFFF;
#pragma unroll
    for (int rf = 0; rf < 2; ++rf) {
      const int base_i = row0 + wvr * 64 + rf * 32 + 4 * hs;
#pragma unroll
      for (int g = 0; g < 4; ++g)
#pragma unroll
        for (int r = 0; r < 4; ++r) {
          const int i = base_i + 8 * g + r;
          const float v = acc[rf][cf][g * 4 + r] * nrv[rf][g * 4 + r];
          if (v > best) { best = v; bi = i; }  // ascending i => first wins
        }
    }
    const float ov = __shfl_xor(best, 32, 64);
    const int oi = __shfl_xor(bi, 32, 64);
    if (ov > best || (ov == best && oi < bi)) { best = ov; bi = oi; }
    if (hs == 0) {
      const unsigned u = __float_as_uint(best);
      const unsigned key = (u & 0x80000000u) ? ~u : (u | 0x80000000u);
      const unsigned long long pk =
          ((unsigned long long)key << 32) | (unsigned)(~(unsigned)bi);
      atomicMax(&packed[j], pk);
    }
  }
}

// ---------------------------------------------------------------------------
// Pass 3: decode packed, apply rsqrt(sty_ss[j]); out[0..A)=nearest,
// out[A..2A)=max_sim.
// ---------------------------------------------------------------------------
__global__ __launch_bounds__(256) void finalize_kernel(
    const unsigned long long* __restrict__ packed,
    const float* __restrict__ sty_ss, float* __restrict__ out) {
  const int j = blockIdx.x * 256 + threadIdx.x;
  if (j >= A_DIM) return;
  const unsigned long long p = packed[j];
  const unsigned key = (unsigned)(p >> 32);
  const unsigned u = (key & 0x80000000u) ? (key ^ 0x80000000u) : ~key;
  const float v = __uint_as_float(u);
  const int idx = (int)(~(unsigned)(p & 0xFFFFFFFFu));
  out[j] = (float)idx;
  out[A_DIM + j] = v * (1.0f / sqrtf(sty_ss[j]));
}

extern "C" void kernel_launch(void* const* d_in, const int* in_sizes, int n_in,
                              void* d_out, int out_size, void* d_ws, size_t ws_size,
                              hipStream_t stream) {
  const float* model = (const float*)d_in[0];  // img side
  const float* style = (const float*)d_in[1];  // sty side
  float* out = (float*)d_out;
  char* ws = (char*)d_ws;

  const size_t usz = (size_t)A_DIM * L_DIM * 2;  // one f16 matrix: 37,748,736 B
  _Float16* img_hi = (_Float16*)(ws);
  _Float16* img_lo = (_Float16*)(ws + usz);
  _Float16* sty_hi = (_Float16*)(ws + 2 * usz);
  _Float16* sty_lo = (_Float16*)(ws + 3 * usz);
  float* img_ss = (float*)(ws + 4 * usz);        // zeroed accumulators
  float* sty_ss = img_ss + A_DIM;
  unsigned long long* packed = (unsigned long long*)(img_ss + 2 * A_DIM);

  // zero ss accumulators (2*A*4 B) + packed (A*8 B) in one contiguous memset
  hipMemsetAsync(img_ss, 0, (size_t)A_DIM * 16, stream);
  prep_kernel<<<dim3(CH / CPB, H_DIM / 3, 2), 256, 0, stream>>>(
      model, style, img_hi, img_lo, sty_hi, sty_lo, img_ss, sty_ss);
  gemm_max_kernel<<<dim3(1296), 256, 0, stream>>>(
      sty_hi, sty_lo, img_hi, img_lo, img_ss, packed);
  finalize_kernel<<<18, 256, 0, stream>>>(packed, sty_ss, out);
}